// Round 3
// baseline (2670.607 us; speedup 1.0000x reference)
//
#include <hip/hip_runtime.h>
#include <hip/hip_bf16.h>
#include <math.h>

// ---------------------------------------------------------------------------
// GCN pipeline, bucketed-destination formulation (no global float scatter):
//  h1 = relu(gcn(x, W1, b1));  h2 = relu(gcn(h1, W2, b2));
//  g = mean-pool(h2, batch);   out = log_softmax(g @ Wfc + bfc)
//
// gcn(x)[i] = dinv[i]*( sum_{j->i} x[j]*dinv[j] + x[i]*dinv[i] ) @ W + b
// Aggregation pre-transform (linearity): 3 dims layer1, 16 dims layer2.
// Destinations partitioned into buckets of BN=256 nodes; per-bucket edge
// lists built once (packed u32: row | localcol<<24); per-bucket workgroups
// accumulate into LDS (padded strides), finalize fused GEMM+ReLU, coalesced
// writes. Mean-pool via global f32 atomics to a small L2-resident table.
// ---------------------------------------------------------------------------

#define TPB 256
#define BN 256          // destination nodes per bucket (== TPB)
#define BSHIFT 8
#define ROWMASK 0xFFFFFF

__device__ __forceinline__ void atomAddF(float* p, float v) {
    unsafeAtomicAdd(p, v);   // hardware global_atomic_add_f32
}

// --- K1: bucket histogram via per-WG LDS counters ---
__global__ void k_bhist(const int* __restrict__ col, int E, int NB, int* __restrict__ bcnt) {
    extern __shared__ int lh[];
    for (int j = threadIdx.x; j < NB; j += TPB) lh[j] = 0;
    __syncthreads();
    int stride = gridDim.x * TPB;
    for (int e = blockIdx.x * TPB + threadIdx.x; e < E; e += stride)
        atomicAdd(&lh[col[e] >> BSHIFT], 1);
    __syncthreads();
    for (int j = threadIdx.x; j < NB; j += TPB)
        if (lh[j]) atomicAdd(&bcnt[j], lh[j]);
}

// --- K2: exclusive scan of bucket counts (NB <= 1024), single block ---
__global__ void k_bscan(const int* __restrict__ bcnt, int NB,
                        int* __restrict__ boff, int* __restrict__ cur) {
    __shared__ int sh[1024];
    const int t = threadIdx.x;
    int v = (t < NB) ? bcnt[t] : 0;
    sh[t] = v;
    __syncthreads();
    for (int d = 1; d < 1024; d <<= 1) {
        int u = (t >= d) ? sh[t - d] : 0;
        __syncthreads();
        sh[t] += u;
        __syncthreads();
    }
    if (t < NB) {
        int excl = (t == 0) ? 0 : sh[t - 1];
        boff[t] = excl;
        cur[t]  = excl;
    }
}

// --- K3: fill bucket edge lists: blist[pos] = row | localcol<<24 ---
__global__ void k_fill(const int* __restrict__ row, const int* __restrict__ col, int E,
                       int* __restrict__ cur, unsigned* __restrict__ blist) {
    int e = blockIdx.x * TPB + threadIdx.x;
    if (e < E) {
        int c = col[e];
        int b = c >> BSHIFT;
        int pos = atomicAdd(&cur[b], 1);
        blist[pos] = (unsigned)row[e] | ((unsigned)(c & (BN - 1)) << 24);
    }
}

// --- K4: per-bucket degree hist -> dinv, y1 = x*dinv (padded float4) ---
__global__ void k_degprep(const unsigned* __restrict__ blist, const int* __restrict__ boff,
                          const int* __restrict__ bcnt, const float* __restrict__ x,
                          float* __restrict__ dinv, float4* __restrict__ y1, int N) {
    __shared__ int h[BN];
    h[threadIdx.x] = 0;
    __syncthreads();
    const int b = blockIdx.x;
    const int s = boff[b], n = bcnt[b];
    for (int k = s + threadIdx.x; k < s + n; k += TPB)
        atomicAdd(&h[blist[k] >> 24], 1);
    __syncthreads();
    const int i = b * BN + threadIdx.x;
    if (i < N) {
        float d = rsqrtf(1.0f + (float)h[threadIdx.x]);
        dinv[i] = d;
        float4 v;
        v.x = x[3 * (size_t)i + 0] * d;
        v.y = x[3 * (size_t)i + 1] * d;
        v.z = x[3 * (size_t)i + 2] * d;
        v.w = 0.0f;
        y1[i] = v;
    }
}

// --- K5: layer1 = LDS-accum gather(3f) + scale + 3x16 GEMM + relu + prescale ---
__global__ void k_layer1(const unsigned* __restrict__ blist, const int* __restrict__ boff,
                         const int* __restrict__ bcnt, const float4* __restrict__ y1,
                         const float* __restrict__ dinv,
                         const float* __restrict__ W1, const float* __restrict__ b1,
                         float* __restrict__ y2, int N) {
    __shared__ float acc[BN * 5];    // stride 5: bank-conflict-free-ish
    __shared__ float sW[48];
    __shared__ float sb[16];
    if (threadIdx.x < 48) sW[threadIdx.x] = W1[threadIdx.x];
    if (threadIdx.x < 16) sb[threadIdx.x] = b1[threadIdx.x];
    for (int j = threadIdx.x; j < BN * 5; j += TPB) acc[j] = 0.0f;
    __syncthreads();
    const int b = blockIdx.x;
    const int s = boff[b], n = bcnt[b];
    for (int k = s + threadIdx.x; k < s + n; k += TPB) {
        unsigned p = blist[k];
        int r = p & ROWMASK, lc = p >> 24;
        float4 v = y1[r];
        atomicAdd(&acc[lc * 5 + 0], v.x);
        atomicAdd(&acc[lc * 5 + 1], v.y);
        atomicAdd(&acc[lc * 5 + 2], v.z);
    }
    __syncthreads();
    const int i = b * BN + threadIdx.x;
    if (i < N) {
        float4 a = y1[i];   // self-loop (already scaled by own dinv)
        float d = dinv[i];
        float ax = (acc[threadIdx.x * 5 + 0] + a.x) * d;
        float ay = (acc[threadIdx.x * 5 + 1] + a.y) * d;
        float az = (acc[threadIdx.x * 5 + 2] + a.z) * d;
        float h[16];
#pragma unroll
        for (int f = 0; f < 16; ++f) {
            float t = sb[f] + ax * sW[f] + ay * sW[16 + f] + az * sW[32 + f];
            h[f] = fmaxf(t, 0.0f) * d;   // relu then pre-scale for next layer
        }
        float4* py = (float4*)(y2 + (size_t)i * 16);
#pragma unroll
        for (int q = 0; q < 4; ++q)
            py[q] = make_float4(h[4*q], h[4*q+1], h[4*q+2], h[4*q+3]);
    }
}

// --- K6: layer2 = LDS-accum gather(16f, 4 thr/edge) + scale + 16x32 GEMM
//          + relu + mean-pool atomics ---
__global__ void k_layer2(const unsigned* __restrict__ blist, const int* __restrict__ boff,
                         const int* __restrict__ bcnt, const float* __restrict__ y2,
                         const float* __restrict__ dinv,
                         const float* __restrict__ W2, const float* __restrict__ b2,
                         const int* __restrict__ batch,
                         float* __restrict__ gsum, float* __restrict__ gcnt, int N) {
    __shared__ float acc[BN * 17];   // stride 17: spreads banks
    __shared__ float sW[512];
    __shared__ float sb[32];
    for (int j = threadIdx.x; j < 512; j += TPB) sW[j] = W2[j];
    if (threadIdx.x < 32) sb[threadIdx.x] = b2[threadIdx.x];
    for (int j = threadIdx.x; j < BN * 17; j += TPB) acc[j] = 0.0f;
    __syncthreads();
    const int b = blockIdx.x;
    const int s = boff[b], n = bcnt[b];
    // 4 threads per edge: lanes q=0..3 read one 64B node record together
    for (int kk = s * 4 + threadIdx.x; kk < (s + n) * 4; kk += TPB) {
        int k = kk >> 2, q = kk & 3;
        unsigned p = blist[k];
        int r = p & ROWMASK, lc = p >> 24;
        float4 v = ((const float4*)(y2 + (size_t)r * 16))[q];
        float* a = &acc[lc * 17 + q * 4];
        atomicAdd(a + 0, v.x);
        atomicAdd(a + 1, v.y);
        atomicAdd(a + 2, v.z);
        atomicAdd(a + 3, v.w);
    }
    __syncthreads();
    const int i = b * BN + threadIdx.x;
    if (i < N) {
        const float d = dinv[i];
        const float4* self = (const float4*)(y2 + (size_t)i * 16);
        float v[16];
#pragma unroll
        for (int q = 0; q < 4; ++q) {
            float4 t = self[q];
            v[4*q+0] = (acc[threadIdx.x * 17 + 4*q + 0] + t.x) * d;
            v[4*q+1] = (acc[threadIdx.x * 17 + 4*q + 1] + t.y) * d;
            v[4*q+2] = (acc[threadIdx.x * 17 + 4*q + 2] + t.z) * d;
            v[4*q+3] = (acc[threadIdx.x * 17 + 4*q + 3] + t.w) * d;
        }
        const int g = batch[i];
        float* gs = gsum + (size_t)g * 32;
#pragma unroll
        for (int f = 0; f < 32; ++f) {
            float t = sb[f];
#pragma unroll
            for (int c = 0; c < 16; ++c) t += v[c] * sW[c * 32 + f];
            atomAddF(&gs[f], fmaxf(t, 0.0f));
        }
        atomAddF(&gcnt[g], 1.0f);
    }
}

// --- K7: mean -> FC -> log_softmax ---
__global__ void k_head(const float* __restrict__ gsum, const float* __restrict__ gcnt,
                       const float* __restrict__ Wfc, const float* __restrict__ bfc,
                       float* __restrict__ out, int G) {
    int g = blockIdx.x * TPB + threadIdx.x;
    if (g < G) {
        float inv = 1.0f / fmaxf(gcnt[g], 1.0f);
        float l0 = bfc[0], l1 = bfc[1];
        const float* gs = gsum + (size_t)g * 32;
#pragma unroll
        for (int j = 0; j < 32; ++j) {
            float m = gs[j] * inv;
            l0 += m * Wfc[j * 2 + 0];
            l1 += m * Wfc[j * 2 + 1];
        }
        float mx = fmaxf(l0, l1);
        float lse = mx + logf(expf(l0 - mx) + expf(l1 - mx));
        out[g * 2 + 0] = l0 - lse;
        out[g * 2 + 1] = l1 - lse;
    }
}

extern "C" void kernel_launch(void* const* d_in, const int* in_sizes, int n_in,
                              void* d_out, int out_size, void* d_ws, size_t ws_size,
                              hipStream_t stream) {
    const float* x     = (const float*)d_in[0];
    const int*   edge  = (const int*)  d_in[1];
    const int*   batch = (const int*)  d_in[2];
    const float* W1    = (const float*)d_in[3];
    const float* b1    = (const float*)d_in[4];
    const float* W2    = (const float*)d_in[5];
    const float* b2    = (const float*)d_in[6];
    const float* Wfc   = (const float*)d_in[7];
    const float* bfc   = (const float*)d_in[8];

    const int N = in_sizes[0] / 3;
    const int E = in_sizes[1] / 2;
    const int G = out_size / 2;
    const int NB = (N + BN - 1) >> BSHIFT;   // buckets
    const int* row = edge;
    const int* col = edge + E;

    // workspace partition (256B aligned)
    char* base = (char*)d_ws;
    size_t o = 0;
    auto take = [&](size_t bytes) { char* r = base + o; o += (bytes + 255) & ~(size_t)255; return r; };
    int*      bcnt  = (int*)     take((size_t)NB * 4);
    int*      boff  = (int*)     take((size_t)NB * 4);
    int*      cur   = (int*)     take((size_t)NB * 4);
    unsigned* blist = (unsigned*)take((size_t)E * 4);
    float*    dinv  = (float*)   take((size_t)N * 4);
    float4*   y1    = (float4*)  take((size_t)N * 16);
    float*    y2    = (float*)   take((size_t)N * 64);
    float*    gsum  = (float*)   take((size_t)G * 33 * 4);
    float*    gcnt  = gsum + (size_t)G * 32;

    hipMemsetAsync(bcnt, 0, (size_t)NB * 4,     stream);
    hipMemsetAsync(gsum, 0, (size_t)G * 33 * 4, stream);

    const int gE = (E + TPB - 1) / TPB;
    const int gG = (G + TPB - 1) / TPB;

    k_bhist  <<<256, TPB, (size_t)NB * 4, stream>>>(col, E, NB, bcnt);
    k_bscan  <<<1, 1024, 0, stream>>>(bcnt, NB, boff, cur);
    k_fill   <<<gE, TPB, 0, stream>>>(row, col, E, cur, blist);
    k_degprep<<<NB, TPB, 0, stream>>>(blist, boff, bcnt, x, dinv, y1, N);
    k_layer1 <<<NB, TPB, 0, stream>>>(blist, boff, bcnt, y1, dinv, W1, b1, y2, N);
    k_layer2 <<<NB, TPB, 0, stream>>>(blist, boff, bcnt, y2, dinv, W2, b2, batch, gsum, gcnt, N);
    k_head   <<<gG, TPB, 0, stream>>>(gsum, gcnt, Wfc, bfc, (float*)d_out, G);
}

// Round 4
// 1291.775 us; speedup vs baseline: 2.0674x; 2.0674x over previous
//
#include <hip/hip_runtime.h>
#include <hip/hip_bf16.h>
#include <math.h>

// ---------------------------------------------------------------------------
// GCN pipeline, super-bucket + LDS-staged binning formulation:
//  h1 = relu(gcn(x, W1, b1));  h2 = relu(gcn(h1, W2, b2));
//  g = mean-pool(h2, batch);   out = log_softmax(g @ Wfc + bfc)
//
// gcn(x)[i] = dinv[i]*( sum_{j->i} x[j]*dinv[j] + x[i]*dinv[i] ) @ W + b
// Aggregation pre-transform (linearity): 3 dims layer1, 16 dims layer2.
// Edges binned once into NB=ceil(N/1024) destination super-buckets
// (LDS-staged, coalesced flush, packed u32 = row | localcol<<18).
// Layer kernels: per (bucket, feature-quarter, edge-slice) block accumulates
// into feature-major LDS (bank = lc%32, conflict-free), dumps partials;
// streaming finalize kernels sum partials + tiny GEMM + ReLU.
// ---------------------------------------------------------------------------

#define TPB 256
#define BSH 10
#define BN 1024            // destination nodes per super-bucket
#define CAPL 32            // staging slots per bucket per 2048-edge chunk
#define NBMAX 256          // static LDS sizing (supports N <= 256K)
#define S1 8               // edge slices, layer 1
#define S2 2               // edge slices, layer 2 (x4 feature quarters)

__device__ __forceinline__ void atomAddF(float* p, float v) {
    unsafeAtomicAdd(p, v);   // hardware global_atomic_add_f32
}

// --- K0: cursor init: cur[b] = b*CAPB ---
__global__ void k_curinit(int* __restrict__ cur, int NB, int CAPB) {
    int t = threadIdx.x;
    if (t < NB) cur[t] = t * CAPB;
}

// --- K1: LDS-staged binning. Each block owns one 2048-edge chunk. ---
__global__ void k_bin(const int* __restrict__ row, const int* __restrict__ col, int E,
                      int NB, int* __restrict__ cur, unsigned* __restrict__ blist) {
    __shared__ unsigned lh[NBMAX * CAPL];
    __shared__ int lcnt[NBMAX];
    __shared__ int gb[NBMAX];
    const int t = threadIdx.x;
    for (int j = t; j < NBMAX; j += TPB) lcnt[j] = 0;
    __syncthreads();
    const int base = blockIdx.x * (TPB * 8);
    int cc[8], rr[8];
#pragma unroll
    for (int j = 0; j < 8; ++j) {
        int e = base + j * TPB + t;
        cc[j] = (e < E) ? col[e] : -1;
        rr[j] = (e < E) ? row[e] : 0;
    }
#pragma unroll
    for (int j = 0; j < 8; ++j) {
        if (cc[j] >= 0) {
            int c = cc[j];
            int b = c >> BSH;
            unsigned val = (unsigned)rr[j] | ((unsigned)(c & (BN - 1)) << 18);
            int pos = atomicAdd(&lcnt[b], 1);
            if (pos < CAPL) lh[b * CAPL + pos] = val;
            else { int gp = atomicAdd(&cur[b], 1); blist[gp] = val; }   // rare spill
        }
    }
    __syncthreads();
    for (int b = t; b < NB; b += TPB) {
        int c = lcnt[b]; if (c > CAPL) c = CAPL;
        gb[b] = c ? atomicAdd(&cur[b], c) : 0;
    }
    __syncthreads();
    const int total = NB * CAPL;
    for (int slot = t; slot < total; slot += TPB) {
        int b = slot >> 5;              // CAPL = 32
        int p = slot & (CAPL - 1);
        int c = lcnt[b]; if (c > CAPL) c = CAPL;
        if (p < c) blist[gb[b] + p] = lh[slot];
    }
}

// --- K2: per-bucket degree hist -> dinv, y1 = x*dinv (padded float4) ---
__global__ void k_deginit(const unsigned* __restrict__ blist, const int* __restrict__ bend,
                          int CAPB, const float* __restrict__ x,
                          float* __restrict__ dinv, float4* __restrict__ y1, int N) {
    __shared__ int hist[BN];
    const int t = threadIdx.x, b = blockIdx.x;
    for (int j = t; j < BN; j += TPB) hist[j] = 0;
    __syncthreads();
    const int lo = b * CAPB, hi = bend[b];
    for (int k = lo + t; k < hi; k += TPB)
        atomicAdd(&hist[blist[k] >> 18], 1);
    __syncthreads();
    for (int j = t; j < BN; j += TPB) {
        int i = b * BN + j;
        if (i < N) {
            float d = rsqrtf(1.0f + (float)hist[j]);
            dinv[i] = d;
            float4 v;
            v.x = x[3 * (size_t)i + 0] * d;
            v.y = x[3 * (size_t)i + 1] * d;
            v.z = x[3 * (size_t)i + 2] * d;
            v.w = 0.0f;
            y1[i] = v;
        }
    }
}

// --- K3: layer1 partial accumulate (bucket x edge-slice), feature-major LDS ---
__global__ void k_layer1(const unsigned* __restrict__ blist, const int* __restrict__ bend,
                         int CAPB, int NB, const float4* __restrict__ y1,
                         float* __restrict__ p1) {
    __shared__ float acc[3 * BN];
    const int t = threadIdx.x;
    const int b = blockIdx.x >> 3;        // S1 = 8
    const int sl = blockIdx.x & 7;
    for (int j = t; j < 3 * BN; j += TPB) acc[j] = 0.0f;
    __syncthreads();
    const int s = b * CAPB, n = bend[b] - s;
    const int len = (n + S1 - 1) / S1;
    int lo = s + sl * len, hi = lo + len;
    const int e2 = s + n; if (hi > e2) hi = e2;
#pragma unroll 4
    for (int k = lo + t; k < hi; k += TPB) {
        unsigned pv = blist[k];
        int r = pv & 0x3FFFF, lc = pv >> 18;
        float4 v = y1[r];
        atomicAdd(&acc[lc],          v.x);
        atomicAdd(&acc[BN + lc],     v.y);
        atomicAdd(&acc[2 * BN + lc], v.z);
    }
    __syncthreads();
    float* out = p1 + ((size_t)(sl * NB + b)) * (3 * BN);
    for (int j = t; j < 3 * BN; j += TPB) out[j] = acc[j];
}

// --- K4: finalize layer1: sum partials + self, scale, 3x16 GEMM, relu, prescale ---
__global__ void k_fin1(const float* __restrict__ p1, const float4* __restrict__ y1,
                       const float* __restrict__ dinv,
                       const float* __restrict__ W1, const float* __restrict__ b1,
                       int NB, float* __restrict__ y2, int N) {
    __shared__ float sW[48];
    __shared__ float sb[16];
    if (threadIdx.x < 48) sW[threadIdx.x] = W1[threadIdx.x];
    if (threadIdx.x < 16) sb[threadIdx.x] = b1[threadIdx.x];
    __syncthreads();
    int i = blockIdx.x * TPB + threadIdx.x;
    if (i >= N) return;
    const int b = i >> BSH, li = i & (BN - 1);
    float4 a = y1[i];                    // self-loop term
    float ax = a.x, ay = a.y, az = a.z;
#pragma unroll
    for (int sl = 0; sl < S1; ++sl) {
        const float* q = p1 + ((size_t)(sl * NB + b)) * (3 * BN);
        ax += q[li]; ay += q[BN + li]; az += q[2 * BN + li];
    }
    const float d = dinv[i];
    ax *= d; ay *= d; az *= d;
    float h[16];
#pragma unroll
    for (int f = 0; f < 16; ++f) {
        float t = sb[f] + ax * sW[f] + ay * sW[16 + f] + az * sW[32 + f];
        h[f] = fmaxf(t, 0.0f) * d;       // relu then pre-scale for next layer
    }
    float4* py = (float4*)(y2 + (size_t)i * 16);
#pragma unroll
    for (int q = 0; q < 4; ++q)
        py[q] = make_float4(h[4*q], h[4*q+1], h[4*q+2], h[4*q+3]);
}

// --- K5: layer2 partial accumulate (bucket x fq x slice), feature-major LDS ---
__global__ void k_layer2(const unsigned* __restrict__ blist, const int* __restrict__ bend,
                         int CAPB, int NB, const float* __restrict__ y2,
                         float* __restrict__ p2) {
    __shared__ float acc[4 * BN];
    const int t = threadIdx.x;
    const int b  = blockIdx.x >> 3;       // layout: b*8 + fq*2 + sl
    const int fq = (blockIdx.x >> 1) & 3;
    const int sl = blockIdx.x & 1;
    for (int j = t; j < 4 * BN; j += TPB) acc[j] = 0.0f;
    __syncthreads();
    const int s = b * CAPB, n = bend[b] - s;
    const int len = (n + S2 - 1) / S2;
    int lo = s + sl * len, hi = lo + len;
    const int e2 = s + n; if (hi > e2) hi = e2;
#pragma unroll 4
    for (int k = lo + t; k < hi; k += TPB) {
        unsigned pv = blist[k];
        int r = pv & 0x3FFFF, lc = pv >> 18;
        float4 v = *(const float4*)(y2 + (size_t)r * 16 + fq * 4);
        atomicAdd(&acc[lc],          v.x);
        atomicAdd(&acc[BN + lc],     v.y);
        atomicAdd(&acc[2 * BN + lc], v.z);
        atomicAdd(&acc[3 * BN + lc], v.w);
    }
    __syncthreads();
    float* out = p2 + ((size_t)((sl * NB + b) * 4 + fq)) * (4 * BN);
    for (int j = t; j < 4 * BN; j += TPB) out[j] = acc[j];
}

// --- K6: finalize layer2: sum partials + self, scale, 16x32 GEMM, relu, pool ---
__global__ void k_fin2pool(const float* __restrict__ p2, const float* __restrict__ y2,
                           const float* __restrict__ dinv,
                           const float* __restrict__ W2, const float* __restrict__ b2,
                           const int* __restrict__ batch, int NB,
                           float* __restrict__ gsum, float* __restrict__ gcnt, int N) {
    __shared__ float sW[512];
    __shared__ float sb[32];
    for (int j = threadIdx.x; j < 512; j += TPB) sW[j] = W2[j];
    if (threadIdx.x < 32) sb[threadIdx.x] = b2[threadIdx.x];
    __syncthreads();
    int i = blockIdx.x * TPB + threadIdx.x;
    if (i >= N) return;
    const int b = i >> BSH, li = i & (BN - 1);
    float v[16];
    const float4* self = (const float4*)(y2 + (size_t)i * 16);
#pragma unroll
    for (int fq = 0; fq < 4; ++fq) {
        float4 sv = self[fq];
        float s0 = sv.x, s1 = sv.y, s2 = sv.z, s3 = sv.w;
#pragma unroll
        for (int sl = 0; sl < S2; ++sl) {
            const float* q = p2 + ((size_t)((sl * NB + b) * 4 + fq)) * (4 * BN);
            s0 += q[li]; s1 += q[BN + li]; s2 += q[2 * BN + li]; s3 += q[3 * BN + li];
        }
        v[fq*4+0] = s0; v[fq*4+1] = s1; v[fq*4+2] = s2; v[fq*4+3] = s3;
    }
    const float d = dinv[i];
#pragma unroll
    for (int c = 0; c < 16; ++c) v[c] *= d;
    const int g = batch[i];
    float* gs = gsum + (size_t)g * 32;
#pragma unroll
    for (int f = 0; f < 32; ++f) {
        float t = sb[f];
#pragma unroll
        for (int c = 0; c < 16; ++c) t += v[c] * sW[c * 32 + f];
        atomAddF(&gs[f], fmaxf(t, 0.0f));
    }
    atomAddF(&gcnt[g], 1.0f);
}

// --- K7: mean -> FC -> log_softmax ---
__global__ void k_head(const float* __restrict__ gsum, const float* __restrict__ gcnt,
                       const float* __restrict__ Wfc, const float* __restrict__ bfc,
                       float* __restrict__ out, int G) {
    int g = blockIdx.x * TPB + threadIdx.x;
    if (g < G) {
        float inv = 1.0f / fmaxf(gcnt[g], 1.0f);
        float l0 = bfc[0], l1 = bfc[1];
        const float* gs = gsum + (size_t)g * 32;
#pragma unroll
        for (int j = 0; j < 32; ++j) {
            float m = gs[j] * inv;
            l0 += m * Wfc[j * 2 + 0];
            l1 += m * Wfc[j * 2 + 1];
        }
        float mx = fmaxf(l0, l1);
        float lse = mx + logf(expf(l0 - mx) + expf(l1 - mx));
        out[g * 2 + 0] = l0 - lse;
        out[g * 2 + 1] = l1 - lse;
    }
}

extern "C" void kernel_launch(void* const* d_in, const int* in_sizes, int n_in,
                              void* d_out, int out_size, void* d_ws, size_t ws_size,
                              hipStream_t stream) {
    const float* x     = (const float*)d_in[0];
    const int*   edge  = (const int*)  d_in[1];
    const int*   batch = (const int*)  d_in[2];
    const float* W1    = (const float*)d_in[3];
    const float* b1    = (const float*)d_in[4];
    const float* W2    = (const float*)d_in[5];
    const float* b2    = (const float*)d_in[6];
    const float* Wfc   = (const float*)d_in[7];
    const float* bfc   = (const float*)d_in[8];

    const int N = in_sizes[0] / 3;
    const int E = in_sizes[1] / 2;
    const int G = out_size / 2;
    const int NB = (N + BN - 1) >> BSH;                  // 196 for N=200000
    const int CAPB = (E + NB - 1) / NB + 4096;           // mean + ~16 sigma slack
    const int* row = edge;
    const int* col = edge + E;

    // workspace partition (256B aligned)
    char* base = (char*)d_ws;
    size_t o = 0;
    auto take = [&](size_t bytes) { char* r = base + o; o += (bytes + 255) & ~(size_t)255; return r; };
    int*      cur   = (int*)     take((size_t)NB * 4);
    unsigned* blist = (unsigned*)take((size_t)NB * CAPB * 4);
    float*    dinv  = (float*)   take((size_t)N * 4);
    float4*   y1    = (float4*)  take((size_t)N * 16);
    float*    y2    = (float*)   take((size_t)N * 64);
    size_t pbytes1 = (size_t)S1 * NB * 3 * BN * 4;       // 19.3 MB
    size_t pbytes2 = (size_t)S2 * NB * 4 * 4 * BN * 4;   // 25.7 MB
    float*    pbuf  = (float*)   take(pbytes1 > pbytes2 ? pbytes1 : pbytes2);
    float*    gsum  = (float*)   take((size_t)G * 33 * 4);
    float*    gcnt  = gsum + (size_t)G * 32;

    hipMemsetAsync(gsum, 0, (size_t)G * 33 * 4, stream);

    const int gBin = (E + TPB * 8 - 1) / (TPB * 8);
    const int gN   = (N + TPB - 1) / TPB;
    const int gG   = (G + TPB - 1) / TPB;

    k_curinit <<<1, TPB, 0, stream>>>(cur, NB, CAPB);
    k_bin     <<<gBin, TPB, 0, stream>>>(row, col, E, NB, cur, blist);
    k_deginit <<<NB, TPB, 0, stream>>>(blist, cur, CAPB, x, dinv, y1, N);
    k_layer1  <<<NB * S1, TPB, 0, stream>>>(blist, cur, CAPB, NB, y1, pbuf);
    k_fin1    <<<gN, TPB, 0, stream>>>(pbuf, y1, dinv, W1, b1, NB, y2, N);
    k_layer2  <<<NB * 4 * S2, TPB, 0, stream>>>(blist, cur, CAPB, NB, y2, pbuf);
    k_fin2pool<<<gN, TPB, 0, stream>>>(pbuf, y2, dinv, W2, b2, batch, NB, gsum, gcnt, N);
    k_head    <<<gG, TPB, 0, stream>>>(gsum, gcnt, Wfc, bfc, (float*)d_out, G);
}